// Round 3
// baseline (617.999 us; speedup 1.0000x reference)
//
#include <hip/hip_runtime.h>
#include <cstddef>

// Bit-exact emulation of a numpy/fp32 reference on an AVX-512 host:
// OpenBLAS DYNAMIC_ARCH maps Zen4/5 + modern Intel to SKYLAKEX kernels.
// sgemm blocking: KC = SGEMM_DEFAULT_Q = 320, single-accumulator 16x4
// microkernel, k sequential within panel. So:
//   cur1 = ((P[0,320) + P[320,640)) + P[640,784)) + b1, all fp32 fma chains.
// Dynamics fp32 with literal numpy op order; layer2 cur2 = (chain + b2) first,
// then nm = mem2*0.25f + cur2.

constexpr int BROWS  = 64;
constexpr int BK     = 16;    // 784 = 49*16; KC=320 boundary at tiles 20,40
constexpr int NJ     = 128;
constexpr int KDIM   = 784;
constexpr int NO     = 10;
constexpr int TSTEPS = 20;

__global__ __launch_bounds__(256, 2) void snn_fused(
    const float* __restrict__ x,
    const float* __restrict__ W1,
    const float* __restrict__ b1,
    const float* __restrict__ W2,
    const float* __restrict__ b2,
    float* __restrict__ out,
    int B)
{
    __shared__ float xs[BROWS][BK + 1];
    __shared__ float ws[NJ][BK + 1];
    __shared__ float w2p[NO][132];                      // padded: bank spread
    __shared__ alignas(16) unsigned short smask[BROWS][8];  // 128 spike bits/row

    const int t  = threadIdx.x;
    const int tx = t & 15;
    const int ty = t >> 4;
    const int r0 = blockIdx.x * BROWS;

    for (int e = t; e < NO * NJ; e += 256) {            // stage W2 (fp32)
        int o = e >> 7, j = e & 127;
        w2p[o][j] = W2[e];
    }

    // ---------------- Phase 1: fp32 GEMM, SKYLAKEX panel emulation ----------
    float acc[4][8], cur[4][8];
    #pragma unroll
    for (int rr = 0; rr < 4; ++rr)
        #pragma unroll
        for (int jj = 0; jj < 8; ++jj) { acc[rr][jj] = 0.0f; cur[rr][jj] = 0.0f; }

    for (int tt = 0; tt < 49; ++tt) {
        const int k0 = tt * BK;
        #pragma unroll
        for (int i = 0; i < 4; ++i) {                   // 64*16 = 4*256
            int e = t + i * 256;
            xs[e >> 4][e & 15] = x[(size_t)(r0 + (e >> 4)) * KDIM + k0 + (e & 15)];
        }
        #pragma unroll
        for (int i = 0; i < 8; ++i) {                   // 128*16 = 8*256
            int e = t + i * 256;
            ws[e >> 4][e & 15] = W1[(size_t)(e >> 4) * KDIM + k0 + (e & 15)];
        }
        __syncthreads();
        #pragma unroll
        for (int kk = 0; kk < BK; ++kk) {               // strict ascending k
            float xv[4], wv[8];
            #pragma unroll
            for (int rr = 0; rr < 4; ++rr) xv[rr] = xs[rr * 16 + ty][kk];
            #pragma unroll
            for (int jj = 0; jj < 8; ++jj) wv[jj] = ws[jj * 16 + tx][kk];
            #pragma unroll
            for (int rr = 0; rr < 4; ++rr)
                #pragma unroll
                for (int jj = 0; jj < 8; ++jj)
                    acc[rr][jj] = fmaf(xv[rr], wv[jj], acc[rr][jj]);
        }
        __syncthreads();
        if (tt == 19) {                                 // end of panel 1 [0,320)
            #pragma unroll
            for (int rr = 0; rr < 4; ++rr)
                #pragma unroll
                for (int jj = 0; jj < 8; ++jj) { cur[rr][jj] = acc[rr][jj]; acc[rr][jj] = 0.0f; }
        } else if (tt == 39) {                          // end of panel 2 [320,640)
            #pragma unroll
            for (int rr = 0; rr < 4; ++rr)
                #pragma unroll
                for (int jj = 0; jj < 8; ++jj) { cur[rr][jj] = cur[rr][jj] + acc[rr][jj]; acc[rr][jj] = 0.0f; }
        }
    }
    #pragma unroll
    for (int jj = 0; jj < 8; ++jj) {                    // + panel 3, + b1
        float bj = b1[jj * 16 + tx];
        #pragma unroll
        for (int rr = 0; rr < 4; ++rr)
            cur[rr][jj] = (cur[rr][jj] + acc[rr][jj]) + bj;
    }

    // ---------------- Phase 2: fp32 LIF dynamics ----------------
    float mem1[4][8];
    #pragma unroll
    for (int rr = 0; rr < 4; ++rr)
        #pragma unroll
        for (int jj = 0; jj < 8; ++jj) mem1[rr][jj] = 0.0f;

    const bool l2 = (t < 160);                          // 16 threads per o
    const int  o  = ty;                                 // t>>4: 0..9 when l2
    const int  rb = tx * 4;                             // 4 rows per thread
    float m2[4]  = {0.f, 0.f, 0.f, 0.f};
    float cnt[4] = {0.f, 0.f, 0.f, 0.f};
    float b2o = 0.0f;
    if (l2) b2o = b2[o];

    float* out0 = out;
    float* rec  = out + (size_t)B * NO;

    for (int st = 0; st < TSTEPS; ++st) {
        float spkf[4][8];
        #pragma unroll
        for (int rr = 0; rr < 4; ++rr)
            #pragma unroll
            for (int jj = 0; jj < 8; ++jj) {
                float m = mem1[rr][jj] * 0.25f + cur[rr][jj];  // *0.25 exact
                float v = m - 1.0f;
                bool  s = v > 0.0f;
                spkf[rr][jj] = s ? 1.0f : 0.0f;
                mem1[rr][jj] = s ? 0.0f : m;
            }
        #pragma unroll
        for (int rr = 0; rr < 4; ++rr) {                // coalesced rec store
            size_t base = ((size_t)st * B + (size_t)(r0 + rr * 16 + ty)) * NJ;
            #pragma unroll
            for (int jj = 0; jj < 8; ++jj)
                rec[base + jj * 16 + tx] = spkf[rr][jj];
        }
        // pack spike bits: row -> 128-bit mask (ascending j)
        #pragma unroll
        for (int rr = 0; rr < 4; ++rr)
            #pragma unroll
            for (int jj = 0; jj < 8; ++jj) {
                unsigned long long bm = __ballot(spkf[rr][jj] != 0.0f);
                if (tx == 0) {
                    int tyl = ty & 3;                   // lane segment in wave
                    smask[rr * 16 + ty][jj] =
                        (unsigned short)((bm >> (tyl * 16)) & 0xFFFFull);
                }
            }
        __syncthreads();
        if (l2) {
            const float4* w4 = (const float4*)&w2p[o][0];
            unsigned int mw[4][4];
            #pragma unroll
            for (int c = 0; c < 4; ++c) {
                const unsigned int* mr = (const unsigned int*)&smask[rb + c][0];
                #pragma unroll
                for (int q = 0; q < 4; ++q) mw[c][q] = mr[q];
            }
            float mm[4] = {0.f, 0.f, 0.f, 0.f};
            #pragma unroll
            for (int q = 0; q < 4; ++q)                 // strict ascending j
                #pragma unroll
                for (int h = 0; h < 8; ++h) {
                    float4 wv = w4[q * 8 + h];
                    int sh = h * 4;
                    #pragma unroll
                    for (int c = 0; c < 4; ++c) {
                        unsigned int bits = mw[c][q] >> sh;
                        mm[c] += (bits & 1u) ? wv.x : 0.0f;
                        mm[c] += (bits & 2u) ? wv.y : 0.0f;
                        mm[c] += (bits & 4u) ? wv.z : 0.0f;
                        mm[c] += (bits & 8u) ? wv.w : 0.0f;
                    }
                }
            #pragma unroll
            for (int c = 0; c < 4; ++c) {
                float cur2 = mm[c] + b2o;               // np: (spk@W2.T) + b2
                float nm   = m2[c] * 0.25f + cur2;      // then decay add
                float v2   = nm - 1.0f;
                bool  s2   = v2 > 0.0f;
                cnt[c] += s2 ? 1.0f : 0.0f;
                m2[c]  = s2 ? 0.0f : nm;
            }
        }
        __syncthreads();
    }

    if (l2) {
        #pragma unroll
        for (int c = 0; c < 4; ++c)
            out0[(size_t)(r0 + rb + c) * NO + o] = cnt[c];
    }
}

extern "C" void kernel_launch(void* const* d_in, const int* in_sizes, int n_in,
                              void* d_out, int out_size, void* d_ws, size_t ws_size,
                              hipStream_t stream)
{
    const float* x  = (const float*)d_in[0];
    const float* W1 = (const float*)d_in[1];
    const float* b1 = (const float*)d_in[2];
    const float* W2 = (const float*)d_in[3];
    const float* b2 = (const float*)d_in[4];
    float* out = (float*)d_out;
    const int B = in_sizes[0] / KDIM;       // 32768
    snn_fused<<<B / BROWS, 256, 0, stream>>>(x, W1, b1, W2, b2, out, B);
}

// Round 4
// 506.911 us; speedup vs baseline: 1.2191x; 1.2191x over previous
//
#include <hip/hip_runtime.h>
#include <cstddef>

// Bit-exact OpenBLAS-skylakex (KC=320) fp32 SNN, optimized:
//  - GEMM: k-major LDS tiles, ds_read_b128 fragments (3 LDS instr / 32 FMA),
//    chunk-swizzled W1 tile (2-way max bank aliasing = free).
//  - Chain order unchanged vs round 3 (PASSED): k ascending, folds at 320/640,
//    ((P1+P2)+P3)+b1; layer2 cur2=mm+b2 then nm=m2*0.25+cur2.
//  - Layer-2: thread=(row, o-group of 4), W2 o-transposed + 2^-(j&31) scaled;
//    bit->float via and+cvt, 4 fmaf per element (products exact).
//  - Parity-buffered spike masks: ONE barrier per timestep.

constexpr int BROWS  = 64;
constexpr int BK     = 16;    // 784 = 49*16; KC=320 folds after tiles 19,39
constexpr int NJ     = 128;
constexpr int KDIM   = 784;
constexpr int NO     = 10;
constexpr int TSTEPS = 20;

__global__ __launch_bounds__(256, 2) void snn_fused(
    const float* __restrict__ x,
    const float* __restrict__ W1,
    const float* __restrict__ b1,
    const float* __restrict__ W2,
    const float* __restrict__ b2,
    float* __restrict__ out,
    int B)
{
    __shared__ alignas(16) float xs[BK][68];     // [kk][row(64)+pad]
    __shared__ alignas(16) float ws[BK][192];    // [kk][16 chunks * 12 (8+4 pad)]
    __shared__ alignas(16) float4 w2s[NJ][3];    // [j][og]: W2[og*4+c][j]*2^-(j&31)
    __shared__ unsigned smaskW[2][BROWS][17];    // parity row masks (17: bank spread)
    __shared__ float b2s[12];

    const int t  = threadIdx.x;
    const int tx = t & 15;                        // col group: j = tx*8+jj
    const int ty = t >> 4;                        // row group: r = ty*4+rr
    const int r0 = blockIdx.x * BROWS;

    // ---- one-time staging: W2 (o-transposed, scaled), b2 ----
    for (int e = t; e < NJ * 3; e += 256) {
        int og = e % 3, j = e / 3;
        float sc = __int_as_float((127 - (j & 31)) << 23);   // 2^-(j&31), exact
        float vv[4];
        #pragma unroll
        for (int c = 0; c < 4; ++c) {
            int o = og * 4 + c;
            vv[c] = (o < NO) ? W2[o * NJ + j] * sc : 0.0f;
        }
        float4 v; v.x = vv[0]; v.y = vv[1]; v.z = vv[2]; v.w = vv[3];
        w2s[j][og] = v;
    }
    if (t < 12) b2s[t] = (t < NO) ? b2[t] : 0.0f;

    // ---- phase 1: fp32 GEMM, panel folds at k=320,640 ----
    float acc[4][8], cur[4][8];
    #pragma unroll
    for (int rr = 0; rr < 4; ++rr)
        #pragma unroll
        for (int jj = 0; jj < 8; ++jj) { acc[rr][jj] = 0.0f; cur[rr][jj] = 0.0f; }

    const int xrow = t >> 2, xkf = (t & 3) * 4;   // x stage: row, 4-k chunk
    const int wj   = t >> 1, wkf = (t & 1) * 8;   // W1 stage: j, 8-k chunk
    const int wco  = wj >> 3, wci = wj & 7;       // chunk / intra
    const float* xrp = x  + (size_t)(r0 + xrow) * KDIM + xkf;
    const float* wrp = W1 + (size_t)wj * KDIM + wkf;

    #pragma unroll 1
    for (int tt = 0; tt < 49; ++tt) {
        const int k0 = tt * BK;
        float4 xv = *(const float4*)(xrp + k0);
        float4 wa = *(const float4*)(wrp + k0);
        float4 wb = *(const float4*)(wrp + k0 + 4);
        xs[xkf + 0][xrow] = xv.x; xs[xkf + 1][xrow] = xv.y;
        xs[xkf + 2][xrow] = xv.z; xs[xkf + 3][xrow] = xv.w;
        float* wp0 = &ws[wkf][wco * 12 + wci];    // rows wkf..wkf+7, stride 192
        wp0[0]    = wa.x; wp0[192]  = wa.y; wp0[384]  = wa.z; wp0[576]  = wa.w;
        wp0[768]  = wb.x; wp0[960]  = wb.y; wp0[1152] = wb.z; wp0[1344] = wb.w;
        __syncthreads();
        #pragma unroll
        for (int kk = 0; kk < BK; ++kk) {         // strict ascending k
            float4 xr  = *(const float4*)&xs[kk][ty * 4];
            float4 wva = *(const float4*)&ws[kk][tx * 12];
            float4 wvb = *(const float4*)&ws[kk][tx * 12 + 4];
            float xf[4] = {xr.x, xr.y, xr.z, xr.w};
            float wf[8] = {wva.x, wva.y, wva.z, wva.w, wvb.x, wvb.y, wvb.z, wvb.w};
            #pragma unroll
            for (int rr = 0; rr < 4; ++rr)
                #pragma unroll
                for (int jj = 0; jj < 8; ++jj)
                    acc[rr][jj] = fmaf(xf[rr], wf[jj], acc[rr][jj]);
        }
        __syncthreads();
        if (tt == 19) {                           // end panel 1 [0,320)
            #pragma unroll
            for (int rr = 0; rr < 4; ++rr)
                #pragma unroll
                for (int jj = 0; jj < 8; ++jj) { cur[rr][jj] = acc[rr][jj]; acc[rr][jj] = 0.0f; }
        } else if (tt == 39) {                    // end panel 2 [320,640)
            #pragma unroll
            for (int rr = 0; rr < 4; ++rr)
                #pragma unroll
                for (int jj = 0; jj < 8; ++jj) { cur[rr][jj] = cur[rr][jj] + acc[rr][jj]; acc[rr][jj] = 0.0f; }
        }
    }
    {
        const float* b1p = b1 + tx * 8;
        float4 ba = *(const float4*)b1p, bb = *(const float4*)(b1p + 4);
        float bf[8] = {ba.x, ba.y, ba.z, ba.w, bb.x, bb.y, bb.z, bb.w};
        #pragma unroll
        for (int rr = 0; rr < 4; ++rr)
            #pragma unroll
            for (int jj = 0; jj < 8; ++jj)
                cur[rr][jj] = (cur[rr][jj] + acc[rr][jj]) + bf[jj];   // +P3, +b1
    }

    // ---- phase 2: LIF dynamics ----
    float mem1[4][8];
    #pragma unroll
    for (int rr = 0; rr < 4; ++rr)
        #pragma unroll
        for (int jj = 0; jj < 8; ++jj) mem1[rr][jj] = 0.0f;

    const int row_l2 = t & 63;                    // layer-2: row
    const int og     = t >> 6;                    // o-group (wave-uniform); 3=idle
    float m2[4]  = {0.f, 0.f, 0.f, 0.f};
    float cnt[4] = {0.f, 0.f, 0.f, 0.f};
    float* rec = out + (size_t)B * NO;

    #pragma unroll 1
    for (int st = 0; st < TSTEPS; ++st) {
        const int p = st & 1;
        #pragma unroll
        for (int rr = 0; rr < 4; ++rr) {
            unsigned bt = 0;
            float s0[8];
            #pragma unroll
            for (int jj = 0; jj < 8; ++jj) {
                float m = fmaf(mem1[rr][jj], 0.25f, cur[rr][jj]);  // *0.25 exact
                float v = m - 1.0f;
                bool  s = v > 0.0f;
                s0[jj] = s ? 1.0f : 0.0f;
                mem1[rr][jj] = s ? 0.0f : m;
                bt |= s ? (1u << jj) : 0u;
            }
            size_t base = ((size_t)st * B + (size_t)(r0 + ty * 4 + rr)) * NJ + tx * 8;
            float4 fa; fa.x = s0[0]; fa.y = s0[1]; fa.z = s0[2]; fa.w = s0[3];
            float4 fb; fb.x = s0[4]; fb.y = s0[5]; fb.z = s0[6]; fb.w = s0[7];
            *(float4*)&rec[base]     = fa;
            *(float4*)&rec[base + 4] = fb;
            ((unsigned char*)&smaskW[p][ty * 4 + rr][0])[tx] = (unsigned char)bt;
        }
        __syncthreads();
        if (og < 3) {
            unsigned mw[4];
            #pragma unroll
            for (int w = 0; w < 4; ++w) mw[w] = smaskW[p][row_l2][w];
            float mm[4] = {0.f, 0.f, 0.f, 0.f};
            #pragma unroll
            for (int w = 0; w < 4; ++w) {
                unsigned bits = mw[w];
                #pragma unroll
                for (int b = 0; b < 32; ++b) {    // strict ascending j
                    float f = (float)(bits & (1u << b));      // 0 or 2^b, exact
                    float4 wv = w2s[w * 32 + b][og];          // W2 * 2^-b
                    mm[0] = fmaf(f, wv.x, mm[0]);
                    mm[1] = fmaf(f, wv.y, mm[1]);
                    mm[2] = fmaf(f, wv.z, mm[2]);
                    mm[3] = fmaf(f, wv.w, mm[3]);
                }
            }
            #pragma unroll
            for (int c = 0; c < 4; ++c) {
                float cur2 = mm[c] + b2s[og * 4 + c];   // np: chain + b2
                float nm   = fmaf(m2[c], 0.25f, cur2);  // then decay add (exact mul)
                float v2   = nm - 1.0f;
                bool  s2   = v2 > 0.0f;
                cnt[c] += s2 ? 1.0f : 0.0f;
                m2[c]  = s2 ? 0.0f : nm;
            }
        }
    }

    if (og < 3) {
        #pragma unroll
        for (int c = 0; c < 4; ++c) {
            int o = og * 4 + c;
            if (o < NO) out[(size_t)(r0 + row_l2) * NO + o] = cnt[c];
        }
    }
}

extern "C" void kernel_launch(void* const* d_in, const int* in_sizes, int n_in,
                              void* d_out, int out_size, void* d_ws, size_t ws_size,
                              hipStream_t stream)
{
    const float* x  = (const float*)d_in[0];
    const float* W1 = (const float*)d_in[1];
    const float* b1 = (const float*)d_in[2];
    const float* W2 = (const float*)d_in[3];
    const float* b2 = (const float*)d_in[4];
    float* out = (float*)d_out;
    const int B = in_sizes[0] / KDIM;       // 32768
    snn_fused<<<B / BROWS, 256, 0, stream>>>(x, W1, b1, W2, b2, out, B);
}